// Round 1
// baseline (2875.248 us; speedup 1.0000x reference)
//
#include <hip/hip_runtime.h>

// ---------------------------------------------------------------------------
// ReadingGCNStage: 3-layer bipartite GCN.
//   deg_r = A.sum(1)+eps ; deg_s = A.sum(0)+eps
//   per layer: m_r=(A@h_s)/deg_r ; m_s=(A^T@h_r)/deg_s
//              h_r' = relu(m_r@Ws + h_r@Wr) ; h_s' = relu(m_s@Vr + h_s@Vs)
// Strategy: everything in bf16 MFMA (16x16x32), m97-style 128x128 GEMM with
// global_load_lds(16B) staging; A and A^T materialized once in bf16; deg-div
// and relu fused into GEMM epilogues; last layer skips the h_s update.
// ---------------------------------------------------------------------------

typedef __bf16 bf16_t;
typedef __attribute__((ext_vector_type(8))) __bf16 bf16x8;
typedef __attribute__((ext_vector_type(4))) float f32x4;

#define N_R 20000
#define N_S 5000
#define DD  512
#define MR_PAD 20096   // 157*128  (M pad for h_r-sized GEMMs)
#define MS_PAD 5120    // 40*128   (M pad for h_s-sized GEMMs)
#define KS_PAD 5024    // N_S padded to mult of 32 (K of A@h_s)
#define KR    20000    // N_R as K dim (already mult of 32)

// ---------------- async global->LDS (16B per lane) ----------------
__device__ __forceinline__ void gll16(const bf16_t* g, bf16_t* l) {
  __builtin_amdgcn_global_load_lds(
      (const __attribute__((address_space(1))) void*)g,
      (__attribute__((address_space(3))) void*)l, 16, 0, 0);
}

// ---------------- prep kernels ----------------

// A f32 [20000][5000] -> Ab bf16 [20096][5024] (zero-padded), deg_r = rowsum+eps
__global__ __launch_bounds__(256) void conv_rowsum_A(
    const float* __restrict__ A, bf16_t* __restrict__ Ab, float* __restrict__ deg_r) {
  int r = blockIdx.x;
  int t = threadIdx.x;
  __shared__ float wsum[4];
  if (r < N_R) {
    float s = 0.f;
    for (int c = t; c < N_S; c += 256) {
      float v = A[(size_t)r * N_S + c];
      s += v;
      Ab[(size_t)r * KS_PAD + c] = (bf16_t)v;
    }
    if (t < KS_PAD - N_S) Ab[(size_t)r * KS_PAD + N_S + t] = (bf16_t)0.f;
    for (int off = 32; off > 0; off >>= 1) s += __shfl_down(s, off, 64);
    if ((t & 63) == 0) wsum[t >> 6] = s;
    __syncthreads();
    if (t == 0) deg_r[r] = wsum[0] + wsum[1] + wsum[2] + wsum[3] + 1e-6f;
  } else {  // zero-fill M-pad rows (feeds MFMA, must not be NaN-ish garbage)
    for (int c = t; c < KS_PAD; c += 256) Ab[(size_t)r * KS_PAD + c] = (bf16_t)0.f;
  }
}

__global__ void init_deg_s(float* __restrict__ deg_s) {
  int i = blockIdx.x * 256 + threadIdx.x;
  if (i < N_S) deg_s[i] = 1e-6f;
}

// Ab bf16 [20096][5024] -> At bf16 [5120][20000]; deg_s += colsums (atomic)
__global__ __launch_bounds__(256) void transpose_A_deg(
    const bf16_t* __restrict__ Ab, bf16_t* __restrict__ At, float* __restrict__ deg_s) {
  __shared__ float tile[64][65];
  __shared__ float csum[4][64];
  int rt = blockIdx.x * 64;   // r tile (313 tiles cover 20000)
  int st = blockIdx.y * 64;   // s tile (80 tiles cover 5120)
  int tx = threadIdx.x & 63;
  int ty = threadIdx.x >> 6;
  int s = st + tx;
  float part = 0.f;
  for (int i = 0; i < 16; ++i) {
    int rr = ty * 16 + i;
    int r = rt + rr;
    float v = 0.f;
    if (r < N_R && s < KS_PAD) v = (float)Ab[(size_t)r * KS_PAD + s];
    tile[rr][tx] = v;
    part += v;
  }
  csum[ty][tx] = part;
  __syncthreads();
  if (ty == 0 && s < N_S)
    atomicAdd(&deg_s[s], csum[0][tx] + csum[1][tx] + csum[2][tx] + csum[3][tx]);
  for (int i = 0; i < 16; ++i) {
    int rr = ty * 16 + i;
    int r = rt + tx;
    if (r < KR) At[(size_t)(st + rr) * KR + r] = (bf16_t)tile[tx][rr];
  }
}

// generic transpose+convert: dst[c][r] = (r<R ? src[r][c] : 0), r in [0,ldd)
template <typename SrcT>
__global__ __launch_bounds__(256) void transpose_to_bf16(
    const SrcT* __restrict__ src, int R, int C, bf16_t* __restrict__ dst, int ldd) {
  __shared__ float tile[64][65];
  int rt = blockIdx.x * 64;
  int ct = blockIdx.y * 64;
  int tx = threadIdx.x & 63;
  int ty = threadIdx.x >> 6;
  for (int i = 0; i < 16; ++i) {
    int rr = ty * 16 + i;
    int r = rt + rr;
    float v = 0.f;
    if (r < R) v = (float)src[(size_t)r * C + ct + tx];
    tile[rr][tx] = v;
  }
  __syncthreads();
  for (int i = 0; i < 16; ++i) {
    int rr = ty * 16 + i;
    int r = rt + tx;
    if (r < ldd) dst[(size_t)(ct + rr) * ldd + r] = (bf16_t)tile[tx][rr];
  }
}

// 12 512x512 weight transposes (z = l*4 + t, t in {Wr,Ws,Vr,Vs})
__global__ __launch_bounds__(256) void transpose_weights(
    const float* __restrict__ Wr, const float* __restrict__ Ws,
    const float* __restrict__ Vr, const float* __restrict__ Vs,
    bf16_t* __restrict__ WT) {
  int z = blockIdx.z;
  int t4 = z & 3, l = z >> 2;
  const float* srcs[4] = {Wr, Ws, Vr, Vs};
  const float* src = srcs[t4] + (size_t)l * DD * DD;
  bf16_t* dst = WT + (size_t)z * DD * DD;
  __shared__ float tile[64][65];
  int rt = blockIdx.x * 64, ct = blockIdx.y * 64;
  int tx = threadIdx.x & 63, ty = threadIdx.x >> 6;
  for (int i = 0; i < 16; ++i) {
    int rr = ty * 16 + i;
    tile[rr][tx] = src[(size_t)(rt + rr) * DD + ct + tx];
  }
  __syncthreads();
  for (int i = 0; i < 16; ++i) {
    int rr = ty * 16 + i;
    dst[(size_t)(ct + rr) * DD + rt + tx] = (bf16_t)tile[tx][rr];
  }
}

// row-major f32 -> bf16 with row padding (C = 512)
__global__ __launch_bounds__(256) void conv_pad(
    const float* __restrict__ src, bf16_t* __restrict__ dst, int R, int Rp) {
  size_t i = (size_t)blockIdx.x * 256 + threadIdx.x;
  size_t tot = (size_t)Rp * DD;
  if (i < tot) {
    int r = (int)(i / DD);
    dst[i] = (r < R) ? (bf16_t)src[i] : (bf16_t)0.f;
  }
}

// ---------------- m97-style bf16 GEMM, B in B^T layout ([N][K] row-major) ----
// C = A1@B1 (+ A2@B2 if HAS2). EPI 0: C/deg[row] -> bf16. EPI 1: relu -> bf16 (+f32 if Cf)
template <bool HAS2, int EPI>
__global__ __launch_bounds__(256) void gemm_bt(
    const bf16_t* __restrict__ A1, const bf16_t* __restrict__ B1, int K1, int lda1, int ldb1,
    const bf16_t* __restrict__ A2, const bf16_t* __restrict__ B2, int K2, int lda2, int ldb2,
    bf16_t* __restrict__ Cb, int Mreal,
    const float* __restrict__ deg, float* __restrict__ Cf) {
  __shared__ bf16_t As[128 * 32];
  __shared__ bf16_t Bs[128 * 32];
  const int tid = threadIdx.x;
  const int lane = tid & 63;
  const int wave = tid >> 6;
  const int m0 = blockIdx.x * 128;
  const int n0 = blockIdx.y * 128;
  // staging: round rr, lane -> row = rr*64 + wave*16 + lane/4, k = (lane%4)*8
  const int srow = wave * 16 + (lane >> 2);
  const int sk = (lane & 3) * 8;
  // compute: wave covers 64x64 quadrant
  const int wm = (wave >> 1) * 64;
  const int wn = (wave & 1) * 64;
  const int lr = lane & 15;
  const int quad = lane >> 4;

  f32x4 acc[4][4] = {};

  const int kt1 = K1 / 32;
  const int ktot = kt1 + (HAS2 ? K2 / 32 : 0);
  for (int kt = 0; kt < ktot; ++kt) {
    const bf16_t* Ap; const bf16_t* Bp; int lda, ldb, k0;
    if (kt < kt1) { Ap = A1; Bp = B1; lda = lda1; ldb = ldb1; k0 = kt * 32; }
    else          { Ap = A2; Bp = B2; lda = lda2; ldb = ldb2; k0 = (kt - kt1) * 32; }
#pragma unroll
    for (int rr = 0; rr < 2; ++rr) {
      gll16(Ap + (size_t)(m0 + rr * 64 + srow) * lda + k0 + sk, &As[rr * 2048 + wave * 512]);
      gll16(Bp + (size_t)(n0 + rr * 64 + srow) * ldb + k0 + sk, &Bs[rr * 2048 + wave * 512]);
    }
    __syncthreads();  // compiler drains vmcnt before s_barrier
    bf16x8 af[4], bq[4];
#pragma unroll
    for (int i = 0; i < 4; ++i) {
      af[i] = *(const bf16x8*)&As[(wm + i * 16 + lr) * 32 + quad * 8];
      bq[i] = *(const bf16x8*)&Bs[(wn + i * 16 + lr) * 32 + quad * 8];
    }
#pragma unroll
    for (int i = 0; i < 4; ++i)
#pragma unroll
      for (int j = 0; j < 4; ++j)
        acc[i][j] = __builtin_amdgcn_mfma_f32_16x16x32_bf16(af[i], bq[j], acc[i][j], 0, 0, 0);
    __syncthreads();
  }

  // epilogue: C/D layout col=lane&15, row=quad*4+reg
#pragma unroll
  for (int i = 0; i < 4; ++i) {
#pragma unroll
    for (int j = 0; j < 4; ++j) {
      int c = n0 + wn + j * 16 + lr;
#pragma unroll
      for (int g = 0; g < 4; ++g) {
        int r = m0 + wm + i * 16 + quad * 4 + g;
        if (r < Mreal) {
          float v = acc[i][j][g];
          if (EPI == 0) v /= deg[r];
          else v = fmaxf(v, 0.f);
          Cb[(size_t)r * DD + c] = (bf16_t)v;
          if (EPI == 1 && Cf != nullptr) Cf[(size_t)r * DD + c] = v;
        }
      }
    }
  }
}

// ---------------- host ----------------
extern "C" void kernel_launch(void* const* d_in, const int* in_sizes, int n_in,
                              void* d_out, int out_size, void* d_ws, size_t ws_size,
                              hipStream_t stream) {
  const float* h_s0 = (const float*)d_in[0];
  const float* A    = (const float*)d_in[1];
  const float* r_em = (const float*)d_in[2];
  const float* Wr   = (const float*)d_in[3];
  const float* Ws   = (const float*)d_in[4];
  const float* Vr   = (const float*)d_in[5];
  const float* Vs   = (const float*)d_in[6];
  float* out = (float*)d_out;

  char* p = (char*)d_ws;
  auto alloc = [&](size_t bytes) {
    char* q = p;
    p += (bytes + 255) & ~(size_t)255;
    return q;
  };
  bf16_t* Ab  = (bf16_t*)alloc((size_t)MR_PAD * KS_PAD * 2);
  bf16_t* At  = (bf16_t*)alloc((size_t)MS_PAD * KR * 2);
  bf16_t* hsT = (bf16_t*)alloc((size_t)DD * KS_PAD * 2);
  bf16_t* hrT = (bf16_t*)alloc((size_t)DD * KR * 2);
  bf16_t* WT  = (bf16_t*)alloc((size_t)12 * DD * DD * 2);
  bf16_t* hs_b[2] = {(bf16_t*)alloc((size_t)MS_PAD * DD * 2), (bf16_t*)alloc((size_t)MS_PAD * DD * 2)};
  bf16_t* hr_b[2] = {(bf16_t*)alloc((size_t)MR_PAD * DD * 2), (bf16_t*)alloc((size_t)MR_PAD * DD * 2)};
  bf16_t* mr_b = (bf16_t*)alloc((size_t)MR_PAD * DD * 2);
  bf16_t* ms_b = (bf16_t*)alloc((size_t)MS_PAD * DD * 2);
  float* deg_r = (float*)alloc((size_t)N_R * 4);
  float* deg_s = (float*)alloc((size_t)N_S * 4);
  if ((size_t)(p - (char*)d_ws) > ws_size) return;  // ws too small: bail loudly

  // ---- prep ----
  conv_rowsum_A<<<MR_PAD, 256, 0, stream>>>(A, Ab, deg_r);
  init_deg_s<<<(N_S + 255) / 256, 256, 0, stream>>>(deg_s);
  transpose_A_deg<<<dim3(313, 80), 256, 0, stream>>>(Ab, At, deg_s);
  transpose_to_bf16<float><<<dim3(79, 8), 256, 0, stream>>>(h_s0, N_S, DD, hsT, KS_PAD);
  transpose_to_bf16<float><<<dim3(313, 8), 256, 0, stream>>>(r_em, N_R, DD, hrT, KR);
  transpose_weights<<<dim3(8, 8, 12), 256, 0, stream>>>(Wr, Ws, Vr, Vs, WT);
  {
    size_t tot = (size_t)MS_PAD * DD;
    conv_pad<<<(int)((tot + 255) / 256), 256, 0, stream>>>(h_s0, hs_b[0], N_S, MS_PAD);
  }
  {
    size_t tot = (size_t)MR_PAD * DD;
    conv_pad<<<(int)((tot + 255) / 256), 256, 0, stream>>>(r_em, hr_b[0], N_R, MR_PAD);
  }

  // ---- layers ----
  int cur = 0;
  for (int l = 0; l < 3; ++l) {
    bf16_t* WrT = WT + ((size_t)l * 4 + 0) * DD * DD;
    bf16_t* WsT = WT + ((size_t)l * 4 + 1) * DD * DD;
    bf16_t* VrT = WT + ((size_t)l * 4 + 2) * DD * DD;
    bf16_t* VsT = WT + ((size_t)l * 4 + 3) * DD * DD;

    // m_r = (A @ h_s) / deg_r   [20000x512]
    gemm_bt<false, 0><<<dim3(157, 4), 256, 0, stream>>>(
        Ab, hsT, KS_PAD, KS_PAD, KS_PAD, nullptr, nullptr, 0, 0, 0,
        mr_b, N_R, deg_r, nullptr);
    if (l < 2) {
      // m_s = (A^T @ h_r) / deg_s   [5000x512]
      gemm_bt<false, 0><<<dim3(40, 4), 256, 0, stream>>>(
          At, hrT, KR, KR, KR, nullptr, nullptr, 0, 0, 0,
          ms_b, N_S, deg_s, nullptr);
    }
    // h_r' = relu(m_r@Ws + h_r@Wr)   (last layer also writes f32 output)
    gemm_bt<true, 1><<<dim3(157, 4), 256, 0, stream>>>(
        mr_b, WsT, DD, DD, DD, hr_b[cur], WrT, DD, DD, DD,
        hr_b[1 - cur], N_R, nullptr, (l == 2) ? out : nullptr);
    if (l < 2) {
      // h_s' = relu(m_s@Vr + h_s@Vs)
      gemm_bt<true, 1><<<dim3(40, 4), 256, 0, stream>>>(
          ms_b, VrT, DD, DD, DD, hs_b[cur], VsT, DD, DD, DD,
          hs_b[1 - cur], N_S, nullptr, nullptr);
      // transposed copies for next layer's bipartite GEMMs
      transpose_to_bf16<bf16_t><<<dim3(313, 8), 256, 0, stream>>>(hr_b[1 - cur], N_R, DD, hrT, KR);
      transpose_to_bf16<bf16_t><<<dim3(79, 8), 256, 0, stream>>>(hs_b[1 - cur], N_S, DD, hsT, KS_PAD);
    }
    cur = 1 - cur;
  }
}

// Round 2
// 2067.785 us; speedup vs baseline: 1.3905x; 1.3905x over previous
//
#include <hip/hip_runtime.h>

// ---------------------------------------------------------------------------
// ReadingGCNStage: 3-layer bipartite GCN, bf16 MFMA (16x16x32).
// R2: BK=64 K-loop (half the barrier drains) + split-K on the two bipartite
// GEMMs (grid 2.4/0.6 blocks/CU -> ~5/CU) with f32 partials + combine kernel.
// ---------------------------------------------------------------------------

typedef __bf16 bf16_t;
typedef __attribute__((ext_vector_type(8))) __bf16 bf16x8;
typedef __attribute__((ext_vector_type(4))) __bf16 bf16x4;
typedef __attribute__((ext_vector_type(4))) float f32x4;

#define N_R 20000
#define N_S 5000
#define DD  512
#define MR_PAD 20096   // 157*128
#define MS_PAD 5120    // 40*128
#define KS_PAD 5056    // 79*64
#define KR_PAD 20224   // 316*64

// async global->LDS: per-lane global addr, LDS dest = wave-uniform base + lane*16B
__device__ __forceinline__ void gll16(const bf16_t* g, bf16_t* l) {
  __builtin_amdgcn_global_load_lds(
      (const __attribute__((address_space(1))) void*)g,
      (__attribute__((address_space(3))) void*)l, 16, 0, 0);
}

// ---------------- prep kernels ----------------

// A f32 [20000][5000] -> Ab bf16 [20096][5056] zero-padded; deg_r = rowsum+eps
__global__ __launch_bounds__(256) void conv_rowsum_A(
    const float* __restrict__ A, bf16_t* __restrict__ Ab, float* __restrict__ deg_r) {
  int r = blockIdx.x;
  int t = threadIdx.x;
  __shared__ float wsum[4];
  if (r < N_R) {
    const float4* Arow = (const float4*)(A + (size_t)r * N_S);  // 5000 = 4*1250, 16B-aligned rows
    float s = 0.f;
    for (int c4 = t; c4 < N_S / 4; c4 += 256) {
      float4 v = Arow[c4];
      s += v.x + v.y + v.z + v.w;
      bf16x4 pv;
      pv[0] = (bf16_t)v.x; pv[1] = (bf16_t)v.y; pv[2] = (bf16_t)v.z; pv[3] = (bf16_t)v.w;
      *(bf16x4*)(Ab + (size_t)r * KS_PAD + 4 * c4) = pv;
    }
    if (t < KS_PAD - N_S) Ab[(size_t)r * KS_PAD + N_S + t] = (bf16_t)0.f;
    for (int off = 32; off > 0; off >>= 1) s += __shfl_down(s, off, 64);
    if ((t & 63) == 0) wsum[t >> 6] = s;
    __syncthreads();
    if (t == 0) deg_r[r] = wsum[0] + wsum[1] + wsum[2] + wsum[3] + 1e-6f;
  } else {
    for (int c = t; c < KS_PAD; c += 256) Ab[(size_t)r * KS_PAD + c] = (bf16_t)0.f;
  }
}

__global__ void init_deg_s(float* __restrict__ deg_s) {
  int i = blockIdx.x * 256 + threadIdx.x;
  if (i < N_S) deg_s[i] = 1e-6f;
}

// Ab [20096][5056] -> At [5120][20224] (zero-padded both dims); deg_s += colsums
__global__ __launch_bounds__(256) void transpose_A_deg(
    const bf16_t* __restrict__ Ab, bf16_t* __restrict__ At, float* __restrict__ deg_s) {
  __shared__ float tile[64][65];
  __shared__ float csum[4][64];
  int rt = blockIdx.x * 64;   // 316 tiles -> 20224
  int st = blockIdx.y * 64;   // 80 tiles  -> 5120
  int tx = threadIdx.x & 63;
  int ty = threadIdx.x >> 6;
  int s = st + tx;
  float part = 0.f;
  for (int i = 0; i < 16; ++i) {
    int rr = ty * 16 + i;
    int r = rt + rr;
    float v = 0.f;
    if (r < N_R && s < KS_PAD) v = (float)Ab[(size_t)r * KS_PAD + s];
    tile[rr][tx] = v;
    part += v;
  }
  csum[ty][tx] = part;
  __syncthreads();
  if (ty == 0 && s < N_S)
    atomicAdd(&deg_s[s], csum[0][tx] + csum[1][tx] + csum[2][tx] + csum[3][tx]);
  for (int i = 0; i < 16; ++i) {
    int rr = ty * 16 + i;
    int r = rt + tx;
    if (r < KR_PAD) At[(size_t)(st + rr) * KR_PAD + r] = (bf16_t)tile[tx][rr];
  }
}

// dst[c][r] = (r<R ? src[r][c] : 0), r in [0,ldd)
template <typename SrcT>
__global__ __launch_bounds__(256) void transpose_to_bf16(
    const SrcT* __restrict__ src, int R, int C, bf16_t* __restrict__ dst, int ldd) {
  __shared__ float tile[64][65];
  int rt = blockIdx.x * 64;
  int ct = blockIdx.y * 64;
  int tx = threadIdx.x & 63;
  int ty = threadIdx.x >> 6;
  for (int i = 0; i < 16; ++i) {
    int rr = ty * 16 + i;
    int r = rt + rr;
    float v = 0.f;
    if (r < R) v = (float)src[(size_t)r * C + ct + tx];
    tile[rr][tx] = v;
  }
  __syncthreads();
  for (int i = 0; i < 16; ++i) {
    int rr = ty * 16 + i;
    int r = rt + tx;
    if (r < ldd) dst[(size_t)(ct + rr) * ldd + r] = (bf16_t)tile[tx][rr];
  }
}

// 12 512x512 weight transposes (z = l*4 + t)
__global__ __launch_bounds__(256) void transpose_weights(
    const float* __restrict__ Wr, const float* __restrict__ Ws,
    const float* __restrict__ Vr, const float* __restrict__ Vs,
    bf16_t* __restrict__ WT) {
  int z = blockIdx.z;
  int t4 = z & 3, l = z >> 2;
  const float* srcs[4] = {Wr, Ws, Vr, Vs};
  const float* src = srcs[t4] + (size_t)l * DD * DD;
  bf16_t* dst = WT + (size_t)z * DD * DD;
  __shared__ float tile[64][65];
  int rt = blockIdx.x * 64, ct = blockIdx.y * 64;
  int tx = threadIdx.x & 63, ty = threadIdx.x >> 6;
  for (int i = 0; i < 16; ++i) {
    int rr = ty * 16 + i;
    tile[rr][tx] = src[(size_t)(rt + rr) * DD + ct + tx];
  }
  __syncthreads();
  for (int i = 0; i < 16; ++i) {
    int rr = ty * 16 + i;
    dst[(size_t)(ct + rr) * DD + rt + tx] = (bf16_t)tile[tx][rr];
  }
}

// row-major f32 -> bf16 with row padding (C = 512)
__global__ __launch_bounds__(256) void conv_pad(
    const float* __restrict__ src, bf16_t* __restrict__ dst, int R, int Rp) {
  size_t i = (size_t)blockIdx.x * 256 + threadIdx.x;
  size_t tot = (size_t)Rp * DD;
  if (i < tot) {
    int r = (int)(i / DD);
    dst[i] = (r < R) ? (bf16_t)src[i] : (bf16_t)0.f;
  }
}

// sum S partial f32 buffers, divide by deg[row], write bf16 (pad rows -> 0)
__global__ __launch_bounds__(256) void combine_div(
    const float* __restrict__ part, int S, size_t stride,
    const float* __restrict__ deg, int Mreal, int Mpad, bf16_t* __restrict__ out) {
  size_t base = ((size_t)blockIdx.x * 256 + threadIdx.x) * 4;
  if (base >= (size_t)Mpad * DD) return;
  f32x4 s = *(const f32x4*)(part + base);
  for (int k = 1; k < S; ++k) s += *(const f32x4*)(part + (size_t)k * stride + base);
  int r = (int)(base >> 9);
  float inv = (r < Mreal) ? 1.0f / deg[r] : 0.f;
  bf16x4 o;
  o[0] = (bf16_t)(s[0] * inv); o[1] = (bf16_t)(s[1] * inv);
  o[2] = (bf16_t)(s[2] * inv); o[3] = (bf16_t)(s[3] * inv);
  *(bf16x4*)(out + base) = o;
}

// ---------------- 128x128 tile, BK=64 GEMM; B given as B^T ([N][K] row-major) -
// LDS layout: two k-half sub-tiles [128 rows][32 elems] each (gll16-compatible,
// 64B/row global transactions, ~8-way LDS read aliasing = measured-harmless).
// EPI 0: C/deg[row]->bf16. EPI 1: relu->bf16 (+f32 Cf). EPI 2: raw f32 to
// Cpart + z*part_stride (split-K partials). z-dim splits K in kt_chunk iters.
template <bool HAS2, int EPI>
__global__ __launch_bounds__(256) void gemm64(
    const bf16_t* __restrict__ A1, const bf16_t* __restrict__ B1, int kt1, int lda1, int ldb1,
    const bf16_t* __restrict__ A2, const bf16_t* __restrict__ B2, int kt2, int lda2, int ldb2,
    int kt_chunk,
    bf16_t* __restrict__ Cb, int Mreal, const float* __restrict__ deg,
    float* __restrict__ Cf, float* __restrict__ Cpart, size_t part_stride) {
  __shared__ bf16_t As[2 * 128 * 32];
  __shared__ bf16_t Bs[2 * 128 * 32];
  const int tid = threadIdx.x;
  const int lane = tid & 63;
  const int wave = tid >> 6;
  const int m0 = blockIdx.x * 128;
  const int n0 = blockIdx.y * 128;
  const int lrow = lane >> 2;          // staging: 16 rows/instr, 64B/row
  const int lcol = (lane & 3) * 8;     // elems within 32-elem half
  const int wm = (wave >> 1) * 64;
  const int wn = (wave & 1) * 64;
  const int lr = lane & 15;
  const int quad = lane >> 4;

  f32x4 acc[4][4] = {};

  const int ktot = kt1 + (HAS2 ? kt2 : 0);
  const int ktb = blockIdx.z * kt_chunk;
  const int kte = (ktb + kt_chunk < ktot) ? ktb + kt_chunk : ktot;

  for (int kt = ktb; kt < kte; ++kt) {
    const bf16_t* Ap; const bf16_t* Bp; int lda, ldb, k0;
    if (!HAS2 || kt < kt1) { Ap = A1; Bp = B1; lda = lda1; ldb = ldb1; k0 = kt * 64; }
    else                   { Ap = A2; Bp = B2; lda = lda2; ldb = ldb2; k0 = (kt - kt1) * 64; }
#pragma unroll
    for (int g = 0; g < 4; ++g) {
      const int h = g >> 1;                      // k-half
      const int rb = (g & 1) * 64 + wave * 16;   // row base for this instr
      gll16(Ap + (size_t)(m0 + rb + lrow) * lda + k0 + h * 32 + lcol,
            &As[h * 4096 + rb * 32]);
      gll16(Bp + (size_t)(n0 + rb + lrow) * ldb + k0 + h * 32 + lcol,
            &Bs[h * 4096 + rb * 32]);
    }
    __syncthreads();
    bf16x8 af[2][4], bq[2][4];
#pragma unroll
    for (int h = 0; h < 2; ++h)
#pragma unroll
      for (int i = 0; i < 4; ++i) {
        af[h][i] = *(const bf16x8*)&As[h * 4096 + (wm + i * 16 + lr) * 32 + quad * 8];
        bq[h][i] = *(const bf16x8*)&Bs[h * 4096 + (wn + i * 16 + lr) * 32 + quad * 8];
      }
#pragma unroll
    for (int h = 0; h < 2; ++h)
#pragma unroll
      for (int i = 0; i < 4; ++i)
#pragma unroll
        for (int j = 0; j < 4; ++j)
          acc[i][j] = __builtin_amdgcn_mfma_f32_16x16x32_bf16(af[h][i], bq[h][j], acc[i][j], 0, 0, 0);
    __syncthreads();
  }

  // C/D layout: col = lane&15, row = quad*4 + reg
  if (EPI == 2) {
    float* P = Cpart + blockIdx.z * part_stride;
#pragma unroll
    for (int i = 0; i < 4; ++i)
#pragma unroll
      for (int j = 0; j < 4; ++j) {
        int c = n0 + wn + j * 16 + lr;
#pragma unroll
        for (int g = 0; g < 4; ++g) {
          int r = m0 + wm + i * 16 + quad * 4 + g;
          P[(size_t)r * DD + c] = acc[i][j][g];
        }
      }
  } else {
#pragma unroll
    for (int i = 0; i < 4; ++i)
#pragma unroll
      for (int j = 0; j < 4; ++j) {
        int c = n0 + wn + j * 16 + lr;
#pragma unroll
        for (int g = 0; g < 4; ++g) {
          int r = m0 + wm + i * 16 + quad * 4 + g;
          if (r < Mreal) {
            float v = acc[i][j][g];
            if (EPI == 0) v /= deg[r];
            else v = fmaxf(v, 0.f);
            Cb[(size_t)r * DD + c] = (bf16_t)v;
            if (EPI == 1 && Cf != nullptr) Cf[(size_t)r * DD + c] = v;
          }
        }
      }
  }
}

// ---------------- host ----------------
extern "C" void kernel_launch(void* const* d_in, const int* in_sizes, int n_in,
                              void* d_out, int out_size, void* d_ws, size_t ws_size,
                              hipStream_t stream) {
  const float* h_s0 = (const float*)d_in[0];
  const float* A    = (const float*)d_in[1];
  const float* r_em = (const float*)d_in[2];
  const float* Wr   = (const float*)d_in[3];
  const float* Ws   = (const float*)d_in[4];
  const float* Vr   = (const float*)d_in[5];
  const float* Vs   = (const float*)d_in[6];
  float* out = (float*)d_out;

  char* p = (char*)d_ws;
  auto alloc = [&](size_t bytes) {
    char* q = p;
    p += (bytes + 255) & ~(size_t)255;
    return q;
  };
  bf16_t* Ab  = (bf16_t*)alloc((size_t)MR_PAD * KS_PAD * 2);
  bf16_t* At  = (bf16_t*)alloc((size_t)MS_PAD * KR_PAD * 2);
  bf16_t* hsT = (bf16_t*)alloc((size_t)DD * KS_PAD * 2);
  bf16_t* hrT = (bf16_t*)alloc((size_t)DD * KR_PAD * 2);
  bf16_t* WT  = (bf16_t*)alloc((size_t)12 * DD * DD * 2);
  bf16_t* hs_b[2] = {(bf16_t*)alloc((size_t)MS_PAD * DD * 2), (bf16_t*)alloc((size_t)MS_PAD * DD * 2)};
  bf16_t* hr_b[2] = {(bf16_t*)alloc((size_t)MR_PAD * DD * 2), (bf16_t*)alloc((size_t)MR_PAD * DD * 2)};
  bf16_t* mr_b = (bf16_t*)alloc((size_t)MR_PAD * DD * 2);
  bf16_t* ms_b = (bf16_t*)alloc((size_t)MS_PAD * DD * 2);
  float* deg_r = (float*)alloc((size_t)N_R * 4);
  float* deg_s = (float*)alloc((size_t)N_S * 4);
  size_t core_bytes = (size_t)(p - (char*)d_ws);
  // split-K partials (shared region, sequential use): max(2 x MR, 8 x MS)
  size_t part_stride_r = (size_t)MR_PAD * DD;            // elems
  size_t part_stride_s = (size_t)MS_PAD * DD;
  size_t part_bytes = (part_stride_s * 8 > part_stride_r * 2 ? part_stride_s * 8 : part_stride_r * 2) * 4;
  bool split_ok = (core_bytes + part_bytes + 256 <= ws_size);
  float* part = split_ok ? (float*)alloc(part_bytes) : nullptr;
  if (core_bytes > ws_size) return;  // can't run at all

  // ---- prep ----
  conv_rowsum_A<<<MR_PAD, 256, 0, stream>>>(A, Ab, deg_r);
  init_deg_s<<<(N_S + 255) / 256, 256, 0, stream>>>(deg_s);
  transpose_A_deg<<<dim3(316, 80), 256, 0, stream>>>(Ab, At, deg_s);
  transpose_to_bf16<float><<<dim3(79, 8), 256, 0, stream>>>(h_s0, N_S, DD, hsT, KS_PAD);
  transpose_to_bf16<float><<<dim3(316, 8), 256, 0, stream>>>(r_em, N_R, DD, hrT, KR_PAD);
  transpose_weights<<<dim3(8, 8, 12), 256, 0, stream>>>(Wr, Ws, Vr, Vs, WT);
  conv_pad<<<(MS_PAD * DD) / 256, 256, 0, stream>>>(h_s0, hs_b[0], N_S, MS_PAD);
  conv_pad<<<(MR_PAD * DD) / 256, 256, 0, stream>>>(r_em, hr_b[0], N_R, MR_PAD);

  const int ktA = KS_PAD / 64;  // 79
  const int ktT = KR_PAD / 64;  // 316

  // ---- layers ----
  int cur = 0;
  for (int l = 0; l < 3; ++l) {
    bf16_t* WrT = WT + ((size_t)l * 4 + 0) * DD * DD;
    bf16_t* WsT = WT + ((size_t)l * 4 + 1) * DD * DD;
    bf16_t* VrT = WT + ((size_t)l * 4 + 2) * DD * DD;
    bf16_t* VsT = WT + ((size_t)l * 4 + 3) * DD * DD;

    // m_r = (A @ h_s) / deg_r   [20000x512], K=5056
    if (split_ok) {
      gemm64<false, 2><<<dim3(157, 4, 2), 256, 0, stream>>>(
          Ab, hsT, ktA, KS_PAD, KS_PAD, nullptr, nullptr, 0, 0, 0,
          40, nullptr, N_R, nullptr, nullptr, part, part_stride_r);
      combine_div<<<MR_PAD / 2, 256, 0, stream>>>(part, 2, part_stride_r, deg_r, N_R, MR_PAD, mr_b);
    } else {
      gemm64<false, 0><<<dim3(157, 4, 1), 256, 0, stream>>>(
          Ab, hsT, ktA, KS_PAD, KS_PAD, nullptr, nullptr, 0, 0, 0,
          ktA, mr_b, N_R, deg_r, nullptr, nullptr, 0);
    }
    if (l < 2) {
      // m_s = (A^T @ h_r) / deg_s   [5000x512], K=20224
      if (split_ok) {
        gemm64<false, 2><<<dim3(40, 4, 8), 256, 0, stream>>>(
            At, hrT, ktT, KR_PAD, KR_PAD, nullptr, nullptr, 0, 0, 0,
            40, nullptr, N_S, nullptr, nullptr, part, part_stride_s);
        combine_div<<<MS_PAD / 2, 256, 0, stream>>>(part, 8, part_stride_s, deg_s, N_S, MS_PAD, ms_b);
      } else {
        gemm64<false, 0><<<dim3(40, 4, 1), 256, 0, stream>>>(
            At, hrT, ktT, KR_PAD, KR_PAD, nullptr, nullptr, 0, 0, 0,
            ktT, ms_b, N_S, deg_s, nullptr, nullptr, 0);
      }
    }
    // h_r' = relu(m_r@Ws + h_r@Wr)
    gemm64<true, 1><<<dim3(157, 4, 1), 256, 0, stream>>>(
        mr_b, WsT, 8, DD, DD, hr_b[cur], WrT, 8, DD, DD,
        16, hr_b[1 - cur], N_R, nullptr, (l == 2) ? out : nullptr, nullptr, 0);
    if (l < 2) {
      // h_s' = relu(m_s@Vr + h_s@Vs)
      gemm64<true, 1><<<dim3(40, 4, 1), 256, 0, stream>>>(
          ms_b, VrT, 8, DD, DD, hs_b[cur], VsT, 8, DD, DD,
          16, hs_b[1 - cur], N_S, nullptr, nullptr, nullptr, 0);
      transpose_to_bf16<bf16_t><<<dim3(316, 8), 256, 0, stream>>>(hr_b[1 - cur], N_R, DD, hrT, KR_PAD);
      transpose_to_bf16<bf16_t><<<dim3(79, 8), 256, 0, stream>>>(hs_b[1 - cur], N_S, DD, hsT, KS_PAD);
    }
    cur = 1 - cur;
  }
}